// Round 8
// baseline (258.678 us; speedup 1.0000x reference)
//
#include <hip/hip_runtime.h>
#include <hip/hip_bf16.h>

#define NN    100000
#define DF    64
#define NPB   32
#define NBLK  (NN / NPB)   // 3125 exact

typedef __bf16 bf16x8 __attribute__((ext_vector_type(8)));
typedef float  f32x4  __attribute__((ext_vector_type(4)));

// tanh-approx gelu, exp2-folded: x / (1 + 2^-(c1*x + c2*x^3))
__device__ __forceinline__ float gelu_f(float x) {
    float u2 = x * (2.302234849f + 0.102953097f * x * x);
    float s  = exp2f(-u2);
    return __fdividef(x, 1.0f + s);
}

__device__ __forceinline__ unsigned cvt_pk_bf16(float lo, float hi) {
    unsigned r;
    asm("v_cvt_pk_bf16_f32 %0, %1, %2" : "=v"(r) : "v"(lo), "v"(hi));
    return r;
}

__global__ __launch_bounds__(256, 4)
void it_fused(const float* __restrict__ y, const float* __restrict__ fy,
              const float* __restrict__ W0, const float* __restrict__ b0,
              const float* __restrict__ W1, const float* __restrict__ b1,
              const int* __restrict__ nbr, const int* __restrict__ splits,
              float* __restrict__ out)
{
    __shared__ int   splitsL[NPB + 1];
    __shared__ float yselfL[NPB][3];
    __shared__ float nodeacc[NPB + 1][DF];                   // +1 dummy row for tail edges
    __shared__ __align__(16) int nsL[4][64];                 // packed nb*64+sg
    __shared__ __align__(16) __bf16 aggW[4][64][8];
    __shared__ __align__(16) __bf16 hL[4][16][DF];

    const int t  = threadIdx.x;
    const int n0 = blockIdx.x * NPB;

    if (t <= NPB) splitsL[t] = splits[n0 + t];
    if (t < NPB) {
        yselfL[t][0] = y[(n0 + t) * 3 + 0];
        yselfL[t][1] = y[(n0 + t) * 3 + 1];
        yselfL[t][2] = y[(n0 + t) * 3 + 2];
    }
    for (int i = t; i < (NPB + 1) * DF / 4; i += 256)
        ((float4*)nodeacc)[i] = make_float4(0, 0, 0, 0);
    __syncthreads();

    const int e_begin = splitsL[0];
    const int e_end   = splitsL[NPB];
    const int lane = t & 63;
    const int wv   = t >> 6;
    const int col  = lane & 15;
    const int kg   = lane >> 4;

    // ---- weight fragments (register-resident) ----
    // Layer 0 as MFMA *A* (swapped): A[m=feat nt*16+col][k=kg*8+j] = W0ext[k][feat];
    // row 6 = b0 (bias via agg[6]=1), rows 7..31 = 0.
    bf16x8 w0f[4];
    #pragma unroll
    for (int nt = 0; nt < 4; nt++)
        #pragma unroll
        for (int j = 0; j < 8; j++) {
            const int k = kg * 8 + j;
            float v = 0.0f;
            if (k < 6)       v = W0[k * DF + nt * 16 + col];
            else if (k == 6) v = b0[nt * 16 + col];
            w0f[nt][j] = (__bf16)v;
        }
    // Layer 1 B-fragments, column-permuted c = col*4 + nt
    bf16x8 w1f[4][2];
    float  b1r[4];
    #pragma unroll
    for (int nt = 0; nt < 4; nt++) {
        b1r[nt] = b1[col * 4 + nt];
        #pragma unroll
        for (int kf = 0; kf < 2; kf++)
            #pragma unroll
            for (int j = 0; j < 8; j++)
                w1f[nt][kf][j] = (__bf16)W1[(kf * 32 + kg * 8 + j) * DF + col * 4 + nt];
    }

    // ---- pipeline prologue: cold-load first batch's (nbr, y) ----
    const int efirst = e_begin + wv * 64 + lane;
    int   nb_cur = 0;
    float ya0 = 0.f, ya1 = 0.f, ya2 = 0.f;
    if (efirst < e_end) {
        nb_cur = nbr[efirst];
        ya0 = y[nb_cur * 3 + 0]; ya1 = y[nb_cur * 3 + 1]; ya2 = y[nb_cur * 3 + 2];
    }

    __bf16* const hw = &hL[wv][0][0];
    const int swz = (col & 7) << 4;

    auto ldfv = [&](int packed) -> float4 {
        return *(const float4*)(fy + (packed >> 6) * DF + col * 4);
    };

    // ---- barrier-free main loop: each wave owns 64-edge batches, stride 256 ----
    for (int ebase = e_begin + wv * 64; ebase < e_end; ebase += 256) {
        const int e = ebase + lane;

        int sg = 0;
        #pragma unroll
        for (int step = 16; step >= 1; step >>= 1)
            if (splitsL[sg + step] <= e) sg += step;
        sg = (e < e_end) ? min(sg, NPB - 1) : NPB;     // tail edges -> dummy row

        nsL[wv][lane] = (nb_cur << 6) | sg;
        bf16x8 ag = {};
        if (e < e_end) {
            ag[0] = (__bf16)ya0; ag[1] = (__bf16)ya1; ag[2] = (__bf16)ya2;
            ag[3] = (__bf16)yselfL[sg][0];
            ag[4] = (__bf16)yselfL[sg][1];
            ag[5] = (__bf16)yselfL[sg][2];
            ag[6] = (__bf16)1.0f;            // bias slot (W0ext row 6 = b0)
        }
        *(bf16x8*)&aggW[wv][lane][0] = ag;

        // prefetch next batch's neighbor index
        const int en = e + 256;
        int nb_nxt = 0;
        if (en < e_end) nb_nxt = nbr[en];

        // ---- prefetch group 0's inputs ----
        int4 q = *(const int4*)&nsL[wv][kg * 4];
        bf16x8 a0 = {};
        if (kg == 0) a0 = *(const bf16x8*)&aggW[wv][col][0];
        float4 f0 = ldfv(q.x), f1 = ldfv(q.y), f2 = ldfv(q.z), f3 = ldfv(q.w);

        #pragma unroll
        for (int g = 0; g < 4; g++) {
            // ---- issue group g+1's prefetches (hide under this group's compute) ----
            int4 qn = q; bf16x8 an = {}; float4 f0n = f0, f1n = f1, f2n = f2, f3n = f3;
            if (g < 3) {
                qn = *(const int4*)&nsL[wv][(g + 1) * 16 + kg * 4];
                if (kg == 0) an = *(const bf16x8*)&aggW[wv][(g + 1) * 16 + col][0];
                f0n = ldfv(qn.x); f1n = ldfv(qn.y); f2n = ldfv(qn.z); f3n = ldfv(qn.w);
            }

            // layer 0 SWAPPED: lane holds h0^T[feat nt*16+kg*4+r][edge=col]
            f32x4 acc0[4] = {};
            #pragma unroll
            for (int nt = 0; nt < 4; nt++)
                acc0[nt] = __builtin_amdgcn_mfma_f32_16x16x32_bf16(w0f[nt], a0, acc0[nt], 0, 0, 0);

            // gelu + pack + 4x ds_write_b64 into hL[edge=col][feature] (swizzled)
            #pragma unroll
            for (int nt = 0; nt < 4; nt++) {
                const unsigned p0 = cvt_pk_bf16(gelu_f(acc0[nt][0]), gelu_f(acc0[nt][1]));
                const unsigned p1 = cvt_pk_bf16(gelu_f(acc0[nt][2]), gelu_f(acc0[nt][3]));
                const int off = col * 128 + ((nt * 32 + kg * 8) ^ swz);
                *(int2*)((char*)hw + off) = make_int2((int)p0, (int)p1);
            }
            bf16x8 af1[2];
            #pragma unroll
            for (int kf = 0; kf < 2; kf++) {
                const int off = col * 128 + ((kf * 64 + kg * 16) ^ swz);
                af1[kf] = *(const bf16x8*)((const char*)hw + off);
            }

            // layer 1: D1[edge=kg*4+r][c=col*4+nt], fp32 accum
            f32x4 acc[4] = {};
            #pragma unroll
            for (int nt = 0; nt < 4; nt++) {
                acc[nt] = __builtin_amdgcn_mfma_f32_16x16x32_bf16(af1[0], w1f[nt][0], acc[nt], 0, 0, 0);
                acc[nt] = __builtin_amdgcn_mfma_f32_16x16x32_bf16(af1[1], w1f[nt][1], acc[nt], 0, 0, 0);
            }

            // gate by prefetched fy rows, segmented-reduce (dummy row absorbs tail)
            const int s0 = q.x & 63, s1 = q.y & 63, s2 = q.z & 63, s3 = q.w & 63;
            #pragma unroll
            for (int nt = 0; nt < 4; nt++) {
                const int   c  = col * 4 + nt;
                const float bb = b1r[nt];
                const float v0 = (acc[nt][0] + bb) * ((const float*)&f0)[nt];
                const float v1 = (acc[nt][1] + bb) * ((const float*)&f1)[nt];
                const float v2 = (acc[nt][2] + bb) * ((const float*)&f2)[nt];
                const float v3 = (acc[nt][3] + bb) * ((const float*)&f3)[nt];
                if (s0 == s3) {   // monotone seg -> all four equal: merged single atomic
                    unsafeAtomicAdd(&nodeacc[s0][c], ((v0 + v1) + (v2 + v3)));
                } else {
                    unsafeAtomicAdd(&nodeacc[s0][c], v0);
                    unsafeAtomicAdd(&nodeacc[s1][c], v1);
                    unsafeAtomicAdd(&nodeacc[s2][c], v2);
                    unsafeAtomicAdd(&nodeacc[s3][c], v3);
                }
            }

            // mid-iter: gather next batch's y (nb_nxt landed under groups 0-1)
            if (g == 1) {
                ya0 = ya1 = ya2 = 0.f;
                if (en < e_end) {
                    ya0 = y[nb_nxt * 3 + 0]; ya1 = y[nb_nxt * 3 + 1]; ya2 = y[nb_nxt * 3 + 2];
                }
                nb_cur = nb_nxt;
            }

            q = qn; a0 = an; f0 = f0n; f1 = f1n; f2 = f2n; f3 = f3n;
        }
    }

    __syncthreads();

    // ---- Epilogue: mean and store (each node owned by exactly this block) ----
    for (int i = t; i < NPB * (DF / 4); i += 256) {
        const int node = i >> 4;
        const int cnt  = splitsL[node + 1] - splitsL[node];
        const float inv = (cnt > 0) ? __fdividef(1.0f, (float)cnt) : 0.0f;
        float4 v = ((const float4*)nodeacc)[i];
        v.x *= inv; v.y *= inv; v.z *= inv; v.w *= inv;
        ((float4*)out)[n0 * (DF / 4) + i] = v;
    }
}

extern "C" void kernel_launch(void* const* d_in, const int* in_sizes, int n_in,
                              void* d_out, int out_size, void* d_ws, size_t ws_size,
                              hipStream_t stream) {
    const float* y   = (const float*)d_in[0];
    const float* fyv = (const float*)d_in[1];
    const float* W0  = (const float*)d_in[2];
    const float* b0  = (const float*)d_in[3];
    const float* W1  = (const float*)d_in[4];
    const float* b1  = (const float*)d_in[5];
    const int*   nb  = (const int*)d_in[6];   // harness delivers integer inputs as int32
    const int*   sp  = (const int*)d_in[7];
    it_fused<<<NBLK, 256, 0, stream>>>(y, fyv, W0, b0, W1, b1, nb, sp, (float*)d_out);
}